// Round 11
// baseline (435.783 us; speedup 1.0000x reference)
//
#include <hip/hip_runtime.h>
#include <math.h>

#define BB 4
#define NN 2048
#define MM 2048
#define HEADS 8
#define DH 64

typedef _Float16 f16;
typedef _Float16 f16x4 __attribute__((ext_vector_type(4)));
typedef _Float16 f16x8 __attribute__((ext_vector_type(8)));
typedef float f32x4 __attribute__((ext_vector_type(4)));
typedef unsigned short ushort;

#define LOG2E 1.44269504088896f
#define QSCALE (0.125f * LOG2E)

#if __has_builtin(__builtin_amdgcn_exp2f)
#define EXP2(x) __builtin_amdgcn_exp2f(x)
#else
#define EXP2(x) exp2f(x)
#endif

__device__ __forceinline__ f16x4 pk4(float a, float b, float c, float d) {
#if __has_builtin(__builtin_amdgcn_cvt_pkrtz)
    auto t0 = __builtin_amdgcn_cvt_pkrtz(a, b);
    auto t1 = __builtin_amdgcn_cvt_pkrtz(c, d);
    f16x4 r;
    r[0] = t0[0]; r[1] = t0[1]; r[2] = t1[0]; r[3] = t1[1];
    return r;
#else
    f16x4 r = {(f16)a, (f16)b, (f16)c, (f16)d};
    return r;
#endif
}

// ---------------------------------------------------------------------------
// Fused weight prep: Wq->[N][K]f16, Wkv->[N][K]f16, Wo->[N][K] f16 hi/lo
// (hi=f16(w), lo=f16(w-hi): 22-bit effective mantissa for the final GEMM).
// 512 blocks: [0,128) Wq, [128,384) Wkv, [384,512) Wo.
// ---------------------------------------------------------------------------
__global__ void wprep_k(const float* __restrict__ Wq, const float* __restrict__ Wkv,
                        const float* __restrict__ Wo,
                        f16* __restrict__ wq16, f16* __restrict__ wkv16,
                        f16* __restrict__ woh, f16* __restrict__ wol)
{
    __shared__ f16 S0[64 * 36], S1[64 * 36];
    const int tid = threadIdx.x;
    const int bid = blockIdx.x;
    const int K = 512;
    const float* W; int N; f16* T16; f16 *Th, *Tl; int id;
    if (bid < 128)      { W = Wq;  N = 512;  T16 = wq16;  Th = 0; Tl = 0; id = bid; }
    else if (bid < 384) { W = Wkv; N = 1024; T16 = wkv16; Th = 0; Tl = 0; id = bid - 128; }
    else                { W = Wo;  N = 512;  T16 = 0; Th = woh; Tl = wol; id = bid - 384; }
    const int k0 = (id & 15) * 32, n0 = (id >> 4) * 64;
    const int kr = tid >> 3, nc = (tid & 7) * 8;
    float4 v0 = *(const float4*)(W + (size_t)(k0 + kr) * N + n0 + nc);
    float4 v1 = *(const float4*)(W + (size_t)(k0 + kr) * N + n0 + nc + 4);
    float e[8] = {v0.x, v0.y, v0.z, v0.w, v1.x, v1.y, v1.z, v1.w};
    const int n = tid >> 2, kc = (tid & 3) * 8;
    if (T16) {
#pragma unroll
        for (int j = 0; j < 8; j++) S0[(nc + j) * 36 + kr] = (f16)e[j];
        __syncthreads();
        *(uint4*)(T16 + (size_t)(n0 + n) * K + k0 + kc) = *(const uint4*)(S0 + n * 36 + kc);
    } else {
#pragma unroll
        for (int j = 0; j < 8; j++) {
            f16 h = (f16)e[j];
            S0[(nc + j) * 36 + kr] = h;
            S1[(nc + j) * 36 + kr] = (f16)(e[j] - (float)h);
        }
        __syncthreads();
        *(uint4*)(Th + (size_t)(n0 + n) * K + k0 + kc) = *(const uint4*)(S0 + n * 36 + kc);
        *(uint4*)(Tl + (size_t)(n0 + n) * K + k0 + kc) = *(const uint4*)(S1 + n * 36 + kc);
    }
}

// ---------------------------------------------------------------------------
// Fused projections: 128x128 tiles, grid (64, 12).
// by 0..3 : Q = tanh(x@Wq)*QSCALE -> qws; by 4..11: K=tanh->kws / V->vt[d][m]
// ---------------------------------------------------------------------------
__launch_bounds__(256)
__global__ void proj_k(const float* __restrict__ x, const float* __restrict__ ctx,
                       const f16* __restrict__ wq16, const f16* __restrict__ wkv16,
                       f16* __restrict__ qws, f16* __restrict__ kws, f16* __restrict__ vt)
{
    __shared__ f16 sA[128 * 36];
    __shared__ f16 sB[128 * 36];

    const int tid  = threadIdx.x;
    const int wave = tid >> 6, lane = tid & 63;
    const int l15  = lane & 15, quad = lane >> 4;
    const int by = blockIdx.y;
    const int isQ = (by < 4);
    const float* A = isQ ? x : ctx;
    const f16* Bt  = isQ ? wq16 : wkv16;
    const int c0 = (isQ ? by : by - 4) * 128;
    const size_t r0 = (size_t)blockIdx.x * 128;
    const int K = 512;

    const int ar = tid >> 1;
    const int ac = (tid & 1) * 16;

    f32x4 acc[2][8] = {};

    for (int k0 = 0; k0 < K; k0 += 32) {
        const float* ap = A + (r0 + ar) * K + k0 + ac;
        float4 a0 = *(const float4*)(ap + 0);
        float4 a1 = *(const float4*)(ap + 4);
        float4 a2 = *(const float4*)(ap + 8);
        float4 a3 = *(const float4*)(ap + 12);
        uint4 bv0 = *(const uint4*)(Bt + (size_t)(c0 + ar) * K + k0 + ac);
        uint4 bv1 = *(const uint4*)(Bt + (size_t)(c0 + ar) * K + k0 + ac + 8);
        f16x8 pa0, pa1;
        pa0[0] = (f16)a0.x; pa0[1] = (f16)a0.y; pa0[2] = (f16)a0.z; pa0[3] = (f16)a0.w;
        pa0[4] = (f16)a1.x; pa0[5] = (f16)a1.y; pa0[6] = (f16)a1.z; pa0[7] = (f16)a1.w;
        pa1[0] = (f16)a2.x; pa1[1] = (f16)a2.y; pa1[2] = (f16)a2.z; pa1[3] = (f16)a2.w;
        pa1[4] = (f16)a3.x; pa1[5] = (f16)a3.y; pa1[6] = (f16)a3.z; pa1[7] = (f16)a3.w;
        __syncthreads();
        *(f16x8*)(sA + ar * 36 + ac)     = pa0;
        *(f16x8*)(sA + ar * 36 + ac + 8) = pa1;
        *(uint4*)(sB + ar * 36 + ac)     = bv0;
        *(uint4*)(sB + ar * 36 + ac + 8) = bv1;
        __syncthreads();

        f16x8 a[2];
#pragma unroll
        for (int rt = 0; rt < 2; rt++)
            a[rt] = *(const f16x8*)(sA + (wave * 32 + rt * 16 + l15) * 36 + quad * 8);
#pragma unroll
        for (int half = 0; half < 2; half++) {
            f16x8 b[4];
#pragma unroll
            for (int c = 0; c < 4; c++)
                b[c] = *(const f16x8*)(sB + ((half * 4 + c) * 16 + l15) * 36 + quad * 8);
#pragma unroll
            for (int rt = 0; rt < 2; rt++)
#pragma unroll
                for (int c = 0; c < 4; c++)
                    acc[rt][half * 4 + c] = __builtin_amdgcn_mfma_f32_16x16x32_f16(
                        a[rt], b[c], acc[rt][half * 4 + c], 0, 0, 0);
        }
    }

    const int b    = (int)(r0 >> 11);
    const int rloc = ((int)(r0 & 2047)) + wave * 32;

#pragma unroll
    for (int rt = 0; rt < 2; rt++)
#pragma unroll
        for (int ct = 0; ct < 8; ct++) {
            const int col = c0 + ct * 16 + l15;
            if (isQ || col < 512) {
                const int h = (col >> 6) & 7;
                const int d = col & 63;
                f16* dst = isQ ? qws : kws;
                const float sc = isQ ? QSCALE : 1.0f;
#pragma unroll
                for (int reg = 0; reg < 4; reg++) {
                    const int nn = rloc + rt * 16 + quad * 4 + reg;
                    dst[(((size_t)b * 8 + h) * 2048 + nn) * 64 + d] =
                        (f16)(tanhf(acc[rt][ct][reg]) * sc);
                }
            } else {
                const int c = col - 512;
                const int h = c >> 6;
                const int d = c & 63;
                const int m0 = rloc + rt * 16 + quad * 4;
                f16x4 pk;
#pragma unroll
                for (int reg = 0; reg < 4; reg++) pk[reg] = (f16)acc[rt][ct][reg];
                *(f16x4*)(vt + (((size_t)b * 8 + h) * 64 + d) * 2048 + m0) = pk;
            }
        }
}

// ---------------------------------------------------------------------------
// MFMA fp16 flash attention v7: j-split x4 (grid (32,16,4) = 2048 blocks =
// 8 blocks/CU; __launch_bounds__(256,8) caps VGPR at 64 = current usage).
// Partials stored NORMALIZED f16: Ohat = O_p / l_p (O(1), f16-safe) + l_p f32.
// Merge: O = sum(Ohat_p * l_p) / sum(l_p) -- exact recombination.
// ---------------------------------------------------------------------------
__launch_bounds__(256, 8)
__global__ void attn_k(const f16* __restrict__ qws, const f16* __restrict__ kws,
                       const f16* __restrict__ vtws,
                       const int* __restrict__ mask, const int* __restrict__ cmask,
                       const float* __restrict__ nk, const float* __restrict__ nv,
                       f16* __restrict__ Opf, float* __restrict__ lp)
{
    __shared__ f16 sK[64 * 72];      // [j][d]
    __shared__ f16 sV[64 * 72];      // [d][j]

    const int tid  = threadIdx.x;
    const int wave = tid >> 6, lane = tid & 63;
    const int l15  = lane & 15, quad = lane >> 4;
    const int bh = blockIdx.x, b = bh >> 3, h = bh & 7;
    const int q0 = blockIdx.y * 128 + wave * 32;
    const int jh = blockIdx.z;

    f16x8 qf[2][2];
    const f16* qbase = qws + ((size_t)bh * NN + q0) * DH;
#pragma unroll
    for (int rt = 0; rt < 2; rt++)
#pragma unroll
        for (int ks = 0; ks < 2; ks++)
            qf[rt][ks] = *(const f16x8*)(qbase + (rt * 16 + l15) * DH + ks * 32 + quad * 8);

    int rowOk[2];
#pragma unroll
    for (int rt = 0; rt < 2; rt++)
        rowOk[rt] = mask[(size_t)b * NN + q0 + rt * 16 + l15];

    float pnull[2] = {0.0f, 0.0f};
    if (jh == 0) {
        float pn[2] = {0.f, 0.f};
#pragma unroll
        for (int ks = 0; ks < 2; ks++)
#pragma unroll
            for (int t = 0; t < 8; t++) {
                const float nkt = tanhf(nk[ks * 32 + quad * 8 + t]);
                pn[0] += (float)qf[0][ks][t] * nkt;
                pn[1] += (float)qf[1][ks][t] * nkt;
            }
#pragma unroll
        for (int rt = 0; rt < 2; rt++) {
            pn[rt] += __shfl_xor(pn[rt], 16);
            pn[rt] += __shfl_xor(pn[rt], 32);
            pnull[rt] = rowOk[rt] ? EXP2(pn[rt]) : 1.0f;
        }
    }
    float negsel[2];
#pragma unroll
    for (int rt = 0; rt < 2; rt++) {
        negsel[rt] = rowOk[rt] ? -1.0e30f : 0.0f;
        if (!rowOk[rt]) {
            const f16x8 zz = {(f16)0, (f16)0, (f16)0, (f16)0, (f16)0, (f16)0, (f16)0, (f16)0};
            qf[rt][0] = zz; qf[rt][1] = zz;
        }
    }

    f32x4 acc[2][4];
    f32x4 accl[2];
#pragma unroll
    for (int rt = 0; rt < 2; rt++)
#pragma unroll
        for (int reg = 0; reg < 4; reg++) {
            const float pr = __shfl(pnull[rt], quad * 4 + reg, 16);
            accl[rt][reg] = pr;
#pragma unroll
            for (int ds = 0; ds < 4; ds++)
                acc[rt][ds][reg] = pr * nv[ds * 16 + l15];
        }

    const f16* kg0 = kws + (size_t)bh * MM * DH;
    const f16* vg0 = vtws + (size_t)bh * DH * MM;
    const int sr = tid >> 2;
    const int sc = (tid & 3) * 16;
    const f16x4 vone = {(f16)1, (f16)1, (f16)1, (f16)1};
    const int jbeg = jh << 9, jend = jbeg + 512;

    for (int jc = jbeg; jc < jend; jc += 64) {
        uint4 kr0 = *(const uint4*)(kg0 + (size_t)(jc + sr) * DH + sc);
        uint4 kr1 = *(const uint4*)(kg0 + (size_t)(jc + sr) * DH + sc + 8);
        uint4 vr0 = *(const uint4*)(vg0 + (size_t)sr * MM + jc + sc);
        uint4 vr1 = *(const uint4*)(vg0 + (size_t)sr * MM + jc + sc + 8);
        int4 cmv[4];
#pragma unroll
        for (int jj = 0; jj < 4; jj++)
            cmv[jj] = *(const int4*)(cmask + (size_t)b * MM + jc + jj * 16 + quad * 4);

        __syncthreads();
        *(uint4*)(sK + sr * 72 + sc)     = kr0;
        *(uint4*)(sK + sr * 72 + sc + 8) = kr1;
        *(uint4*)(sV + sr * 72 + sc)     = vr0;
        *(uint4*)(sV + sr * 72 + sc + 8) = vr1;
        __syncthreads();

        f32x4 st[2][4];
#pragma unroll
        for (int rt = 0; rt < 2; rt++)
#pragma unroll
            for (int jj = 0; jj < 4; jj++) {
                st[rt][jj][0] = cmv[jj].x ? 0.0f : negsel[rt];
                st[rt][jj][1] = cmv[jj].y ? 0.0f : negsel[rt];
                st[rt][jj][2] = cmv[jj].z ? 0.0f : negsel[rt];
                st[rt][jj][3] = cmv[jj].w ? 0.0f : negsel[rt];
            }

#pragma unroll
        for (int ks = 0; ks < 2; ks++) {
            f16x8 kb[4];
#pragma unroll
            for (int jj = 0; jj < 4; jj++)
                kb[jj] = *(const f16x8*)(sK + (jj * 16 + l15) * 72 + ks * 32 + quad * 8);
#pragma unroll
            for (int rt = 0; rt < 2; rt++)
#pragma unroll
                for (int jj = 0; jj < 4; jj++)
                    st[rt][jj] = __builtin_amdgcn_mfma_f32_16x16x32_f16(
                        kb[jj], qf[rt][ks], st[rt][jj], 0, 0, 0);
        }

        f16x4 pa[2][4];
#pragma unroll
        for (int rt = 0; rt < 2; rt++)
#pragma unroll
            for (int jj = 0; jj < 4; jj++)
                pa[rt][jj] = pk4(EXP2(st[rt][jj][0]), EXP2(st[rt][jj][1]),
                                 EXP2(st[rt][jj][2]), EXP2(st[rt][jj][3]));

#pragma unroll
        for (int jj = 0; jj < 4; jj++) {
            f16x4 vb[4];
#pragma unroll
            for (int ds = 0; ds < 4; ds++)
                vb[ds] = *(const f16x4*)(sV + (ds * 16 + l15) * 72 + jj * 16 + quad * 4);
#pragma unroll
            for (int rt = 0; rt < 2; rt++) {
#pragma unroll
                for (int ds = 0; ds < 4; ds++)
                    acc[rt][ds] = __builtin_amdgcn_mfma_f32_16x16x16f16(
                        pa[rt][jj], vb[ds], acc[rt][ds], 0, 0, 0);
                accl[rt] = __builtin_amdgcn_mfma_f32_16x16x16f16(
                    pa[rt][jj], vone, accl[rt], 0, 0, 0);
            }
        }
    }

    // epilogue: normalized f16 partials + l
#pragma unroll
    for (int rt = 0; rt < 2; rt++) {
        float inv[4];
#pragma unroll
        for (int reg = 0; reg < 4; reg++)
            inv[reg] = 1.0f / fmaxf(accl[rt][reg], 1e-35f);
#pragma unroll
        for (int ds = 0; ds < 4; ds++)
#pragma unroll
            for (int reg = 0; reg < 4; reg++) {
                const int r = q0 + rt * 16 + quad * 4 + reg;
                Opf[((size_t)jh * 8192 + b * 2048 + r) * 512 + h * 64 + ds * 16 + l15] =
                    (f16)(acc[rt][ds][reg] * inv[reg]);
            }
    }
    if (l15 == 0) {
#pragma unroll
        for (int rt = 0; rt < 2; rt++)
#pragma unroll
            for (int reg = 0; reg < 4; reg++)
                lp[((size_t)jh * 32 + bh) * 2048 + q0 + rt * 16 + quad * 4 + reg] =
                    accl[rt][reg];
    }
}

// ---------------------------------------------------------------------------
// Merge 4 j-partials: O = sum(Ohat_p * l_p) / sum(l_p) -> f16 of16.
// ---------------------------------------------------------------------------
__global__ void merge_k(const f16* __restrict__ Opf, const float* __restrict__ lp,
                        f16* __restrict__ of16)
{
    const int i = blockIdx.x * 256 + threadIdx.x;   // 1,048,576 threads
    const int row = i >> 7;                          // 0..8191
    const int c4  = i & 127;
    const int b = row >> 11, n = row & 2047, h = c4 >> 4;
    float w[4], den = 0.f;
#pragma unroll
    for (int jh = 0; jh < 4; jh++) {
        w[jh] = lp[((size_t)jh * 32 + b * 8 + h) * 2048 + n];
        den += w[jh];
    }
    const float inv = 1.0f / den;
    float v0 = 0, v1 = 0, v2 = 0, v3 = 0;
#pragma unroll
    for (int jh = 0; jh < 4; jh++) {
        f16x4 o = *(const f16x4*)(Opf + ((size_t)jh * 8192 + row) * 512 + c4 * 4);
        v0 += (float)o[0] * w[jh];
        v1 += (float)o[1] * w[jh];
        v2 += (float)o[2] * w[jh];
        v3 += (float)o[3] * w[jh];
    }
    f16x4 r = pk4(v0 * inv, v1 * inv, v2 * inv, v3 * inv);
    *(f16x4*)(of16 + (size_t)row * 512 + c4 * 4) = r;
}

// ---------------------------------------------------------------------------
// Final GEMM: out = O(f16) @ Wo(f16 hi/lo) + bias.  2 MFMAs per sub-tile:
// a*bh + a*bl gives ~22-bit-effective Wo; O's f16 rounding is the only loss.
// ---------------------------------------------------------------------------
__launch_bounds__(256)
__global__ void mgemm2(const f16* __restrict__ A, const f16* __restrict__ Bh,
                       const f16* __restrict__ Bl,
                       float* __restrict__ o32, const float* __restrict__ bias,
                       int K)
{
    __shared__ f16 sA[128 * 36];
    __shared__ f16 sBh[64 * 36], sBl[64 * 36];

    const int tid  = threadIdx.x;
    const int wave = tid >> 6, lane = tid & 63;
    const int l15  = lane & 15, quad = lane >> 4;
    const size_t r0 = (size_t)blockIdx.x * 128;
    const int c0 = blockIdx.y * 64;

    const int sr = tid >> 2;
    const int sc = (tid & 3) * 8;

    f32x4 acc[2][4] = {};

    for (int k0 = 0; k0 < K; k0 += 32) {
        uint4 a0 = *(const uint4*)(A + (r0 + sr) * K + k0 + sc);
        uint4 a1 = *(const uint4*)(A + (r0 + 64 + sr) * K + k0 + sc);
        uint4 bh = *(const uint4*)(Bh + (size_t)(c0 + sr) * K + k0 + sc);
        uint4 bl = *(const uint4*)(Bl + (size_t)(c0 + sr) * K + k0 + sc);
        __syncthreads();
        *(uint4*)(sA + sr * 36 + sc)        = a0;
        *(uint4*)(sA + (64 + sr) * 36 + sc) = a1;
        *(uint4*)(sBh + sr * 36 + sc)       = bh;
        *(uint4*)(sBl + sr * 36 + sc)       = bl;
        __syncthreads();

        f16x8 a[2], b_h[4], b_l[4];
#pragma unroll
        for (int rt = 0; rt < 2; rt++)
            a[rt] = *(const f16x8*)(sA + (wave * 32 + rt * 16 + l15) * 36 + quad * 8);
#pragma unroll
        for (int ct = 0; ct < 4; ct++) {
            b_h[ct] = *(const f16x8*)(sBh + (ct * 16 + l15) * 36 + quad * 8);
            b_l[ct] = *(const f16x8*)(sBl + (ct * 16 + l15) * 36 + quad * 8);
        }
#pragma unroll
        for (int rt = 0; rt < 2; rt++)
#pragma unroll
            for (int ct = 0; ct < 4; ct++) {
                acc[rt][ct] = __builtin_amdgcn_mfma_f32_16x16x32_f16(a[rt], b_h[ct], acc[rt][ct], 0, 0, 0);
                acc[rt][ct] = __builtin_amdgcn_mfma_f32_16x16x32_f16(a[rt], b_l[ct], acc[rt][ct], 0, 0, 0);
            }
    }

#pragma unroll
    for (int rt = 0; rt < 2; rt++)
#pragma unroll
        for (int ct = 0; ct < 4; ct++) {
            const int col = c0 + ct * 16 + l15;
            const float bv = bias[col];
#pragma unroll
            for (int reg = 0; reg < 4; reg++) {
                const size_t row = r0 + wave * 32 + rt * 16 + quad * 4 + reg;
                o32[row * 512 + col] = acc[rt][ct][reg] + bv;
            }
        }
}

extern "C" void kernel_launch(void* const* d_in, const int* in_sizes, int n_in,
                              void* d_out, int out_size, void* d_ws, size_t ws_size,
                              hipStream_t stream)
{
    const float* x    = (const float*)d_in[0];
    const float* ctx  = (const float*)d_in[1];
    const int*   mask = (const int*)d_in[2];
    const int*   cmsk = (const int*)d_in[3];
    const float* Wq   = (const float*)d_in[4];
    const float* Wkv  = (const float*)d_in[5];
    const float* Wo   = (const float*)d_in[6];
    const float* bo   = (const float*)d_in[7];
    const float* nk   = (const float*)d_in[8];
    const float* nv   = (const float*)d_in[9];
    float* out = (float*)d_out;

    const size_t S = (size_t)BB * HEADS * NN * DH;  // 4,194,304 elems

    f16* qws = (f16*)d_ws;                  // 8 MB
    f16* kws = qws + S;                     // 8 MB
    f16* vt  = kws + S;                     // 8 MB
    f16* wq16  = vt + S;                    // 0.5 MB
    f16* wkv16 = wq16 + 512 * 512;          // 1 MB
    f16* woh = wkv16 + 512 * 1024;          // 0.5 MB
    f16* wol = woh + 512 * 512;             // 0.5 MB
    float* lp = (float*)(wol + 512 * 512);  // 4*32*2048*4 = 1 MB
    f16* Opf = (f16*)(lp + 4 * 32 * 2048);  // 4*8192*512*2 = 32 MB
    f16* of16 = qws;                        // alias (qws dead after attn_k)

    wprep_k<<<512, 256, 0, stream>>>(Wq, Wkv, Wo, wq16, wkv16, woh, wol);
    proj_k<<<dim3(64, 12), 256, 0, stream>>>(x, ctx, wq16, wkv16, qws, kws, vt);
    attn_k<<<dim3(32, 16, 4), 256, 0, stream>>>(qws, kws, vt, mask, cmsk, nk, nv, Opf, lp);
    merge_k<<<4096, 256, 0, stream>>>(Opf, lp, of16);
    mgemm2<<<dim3(64, 8), 256, 0, stream>>>(of16, woh, wol, out, bo, 512);
}

// Round 12
// 193.950 us; speedup vs baseline: 2.2469x; 2.2469x over previous
//
#include <hip/hip_runtime.h>
#include <math.h>

#define BB 4
#define NN 2048
#define MM 2048
#define HEADS 8
#define DH 64

typedef _Float16 f16;
typedef _Float16 f16x4 __attribute__((ext_vector_type(4)));
typedef _Float16 f16x8 __attribute__((ext_vector_type(8)));
typedef float f32x4 __attribute__((ext_vector_type(4)));
typedef unsigned short ushort;

#define LOG2E 1.44269504088896f
#define QSCALE (0.125f * LOG2E)

#if __has_builtin(__builtin_amdgcn_exp2f)
#define EXP2(x) __builtin_amdgcn_exp2f(x)
#else
#define EXP2(x) exp2f(x)
#endif

__device__ __forceinline__ f16x4 pk4(float a, float b, float c, float d) {
#if __has_builtin(__builtin_amdgcn_cvt_pkrtz)
    auto t0 = __builtin_amdgcn_cvt_pkrtz(a, b);
    auto t1 = __builtin_amdgcn_cvt_pkrtz(c, d);
    f16x4 r;
    r[0] = t0[0]; r[1] = t0[1]; r[2] = t1[0]; r[3] = t1[1];
    return r;
#else
    f16x4 r = {(f16)a, (f16)b, (f16)c, (f16)d};
    return r;
#endif
}

// ---------------------------------------------------------------------------
// Fused weight prep: Wq->[N][K]f16, Wkv->[N][K]f16, Wo->[N][K] f16 hi/lo
// (hi=f16(w), lo=f16(w-hi): ~22-bit effective mantissa for the final GEMM).
// 512 blocks: [0,128) Wq, [128,384) Wkv, [384,512) Wo.
// ---------------------------------------------------------------------------
__global__ void wprep_k(const float* __restrict__ Wq, const float* __restrict__ Wkv,
                        const float* __restrict__ Wo,
                        f16* __restrict__ wq16, f16* __restrict__ wkv16,
                        f16* __restrict__ woh, f16* __restrict__ wol)
{
    __shared__ f16 S0[64 * 36], S1[64 * 36];
    const int tid = threadIdx.x;
    const int bid = blockIdx.x;
    const int K = 512;
    const float* W; int N; f16* T16; f16 *Th, *Tl; int id;
    if (bid < 128)      { W = Wq;  N = 512;  T16 = wq16;  Th = 0; Tl = 0; id = bid; }
    else if (bid < 384) { W = Wkv; N = 1024; T16 = wkv16; Th = 0; Tl = 0; id = bid - 128; }
    else                { W = Wo;  N = 512;  T16 = 0; Th = woh; Tl = wol; id = bid - 384; }
    const int k0 = (id & 15) * 32, n0 = (id >> 4) * 64;
    const int kr = tid >> 3, nc = (tid & 7) * 8;
    float4 v0 = *(const float4*)(W + (size_t)(k0 + kr) * N + n0 + nc);
    float4 v1 = *(const float4*)(W + (size_t)(k0 + kr) * N + n0 + nc + 4);
    float e[8] = {v0.x, v0.y, v0.z, v0.w, v1.x, v1.y, v1.z, v1.w};
    const int n = tid >> 2, kc = (tid & 3) * 8;
    if (T16) {
#pragma unroll
        for (int j = 0; j < 8; j++) S0[(nc + j) * 36 + kr] = (f16)e[j];
        __syncthreads();
        *(uint4*)(T16 + (size_t)(n0 + n) * K + k0 + kc) = *(const uint4*)(S0 + n * 36 + kc);
    } else {
#pragma unroll
        for (int j = 0; j < 8; j++) {
            f16 h = (f16)e[j];
            S0[(nc + j) * 36 + kr] = h;
            S1[(nc + j) * 36 + kr] = (f16)(e[j] - (float)h);
        }
        __syncthreads();
        *(uint4*)(Th + (size_t)(n0 + n) * K + k0 + kc) = *(const uint4*)(S0 + n * 36 + kc);
        *(uint4*)(Tl + (size_t)(n0 + n) * K + k0 + kc) = *(const uint4*)(S1 + n * 36 + kc);
    }
}

// ---------------------------------------------------------------------------
// Fused projections: 128x128 tiles, grid (64, 12).
// by 0..3 : Q = tanh(x@Wq)*QSCALE -> qws; by 4..11: K=tanh->kws / V->vt[d][m]
// ---------------------------------------------------------------------------
__launch_bounds__(256)
__global__ void proj_k(const float* __restrict__ x, const float* __restrict__ ctx,
                       const f16* __restrict__ wq16, const f16* __restrict__ wkv16,
                       f16* __restrict__ qws, f16* __restrict__ kws, f16* __restrict__ vt)
{
    __shared__ f16 sA[128 * 36];
    __shared__ f16 sB[128 * 36];

    const int tid  = threadIdx.x;
    const int wave = tid >> 6, lane = tid & 63;
    const int l15  = lane & 15, quad = lane >> 4;
    const int by = blockIdx.y;
    const int isQ = (by < 4);
    const float* A = isQ ? x : ctx;
    const f16* Bt  = isQ ? wq16 : wkv16;
    const int c0 = (isQ ? by : by - 4) * 128;
    const size_t r0 = (size_t)blockIdx.x * 128;
    const int K = 512;

    const int ar = tid >> 1;
    const int ac = (tid & 1) * 16;

    f32x4 acc[2][8] = {};

    for (int k0 = 0; k0 < K; k0 += 32) {
        const float* ap = A + (r0 + ar) * K + k0 + ac;
        float4 a0 = *(const float4*)(ap + 0);
        float4 a1 = *(const float4*)(ap + 4);
        float4 a2 = *(const float4*)(ap + 8);
        float4 a3 = *(const float4*)(ap + 12);
        uint4 bv0 = *(const uint4*)(Bt + (size_t)(c0 + ar) * K + k0 + ac);
        uint4 bv1 = *(const uint4*)(Bt + (size_t)(c0 + ar) * K + k0 + ac + 8);
        f16x8 pa0, pa1;
        pa0[0] = (f16)a0.x; pa0[1] = (f16)a0.y; pa0[2] = (f16)a0.z; pa0[3] = (f16)a0.w;
        pa0[4] = (f16)a1.x; pa0[5] = (f16)a1.y; pa0[6] = (f16)a1.z; pa0[7] = (f16)a1.w;
        pa1[0] = (f16)a2.x; pa1[1] = (f16)a2.y; pa1[2] = (f16)a2.z; pa1[3] = (f16)a2.w;
        pa1[4] = (f16)a3.x; pa1[5] = (f16)a3.y; pa1[6] = (f16)a3.z; pa1[7] = (f16)a3.w;
        __syncthreads();
        *(f16x8*)(sA + ar * 36 + ac)     = pa0;
        *(f16x8*)(sA + ar * 36 + ac + 8) = pa1;
        *(uint4*)(sB + ar * 36 + ac)     = bv0;
        *(uint4*)(sB + ar * 36 + ac + 8) = bv1;
        __syncthreads();

        f16x8 a[2];
#pragma unroll
        for (int rt = 0; rt < 2; rt++)
            a[rt] = *(const f16x8*)(sA + (wave * 32 + rt * 16 + l15) * 36 + quad * 8);
#pragma unroll
        for (int half = 0; half < 2; half++) {
            f16x8 b[4];
#pragma unroll
            for (int c = 0; c < 4; c++)
                b[c] = *(const f16x8*)(sB + ((half * 4 + c) * 16 + l15) * 36 + quad * 8);
#pragma unroll
            for (int rt = 0; rt < 2; rt++)
#pragma unroll
                for (int c = 0; c < 4; c++)
                    acc[rt][half * 4 + c] = __builtin_amdgcn_mfma_f32_16x16x32_f16(
                        a[rt], b[c], acc[rt][half * 4 + c], 0, 0, 0);
        }
    }

    const int b    = (int)(r0 >> 11);
    const int rloc = ((int)(r0 & 2047)) + wave * 32;

#pragma unroll
    for (int rt = 0; rt < 2; rt++)
#pragma unroll
        for (int ct = 0; ct < 8; ct++) {
            const int col = c0 + ct * 16 + l15;
            if (isQ || col < 512) {
                const int h = (col >> 6) & 7;
                const int d = col & 63;
                f16* dst = isQ ? qws : kws;
                const float sc = isQ ? QSCALE : 1.0f;
#pragma unroll
                for (int reg = 0; reg < 4; reg++) {
                    const int nn = rloc + rt * 16 + quad * 4 + reg;
                    dst[(((size_t)b * 8 + h) * 2048 + nn) * 64 + d] =
                        (f16)(tanhf(acc[rt][ct][reg]) * sc);
                }
            } else {
                const int c = col - 512;
                const int h = c >> 6;
                const int d = c & 63;
                const int m0 = rloc + rt * 16 + quad * 4;
                f16x4 pk;
#pragma unroll
                for (int reg = 0; reg < 4; reg++) pk[reg] = (f16)acc[rt][ct][reg];
                *(f16x4*)(vt + (((size_t)b * 8 + h) * 64 + d) * 2048 + m0) = pk;
            }
        }
}

// ---------------------------------------------------------------------------
// MFMA fp16 flash attention v8 = v7 j-split x4 with the spill fixed:
// __launch_bounds__(256, 4) (128-VGPR budget; actual alloc ~64). Occupancy is
// set by ACTUAL allocation: VGPR 64 + LDS 18.4 KB -> 8 blocks/CU, and the
// 2048-block grid supplies them. NEVER force min-waves past live-reg count
// (round-11 lesson: (256,8) -> 32 VGPRs -> 1.3 GB spill traffic).
// Partials stored NORMALIZED f16: Ohat = O_p / l_p + l_p f32.
// Merge: O = sum(Ohat_p * l_p) / sum(l_p).
// ---------------------------------------------------------------------------
__launch_bounds__(256, 4)
__global__ void attn_k(const f16* __restrict__ qws, const f16* __restrict__ kws,
                       const f16* __restrict__ vtws,
                       const int* __restrict__ mask, const int* __restrict__ cmask,
                       const float* __restrict__ nk, const float* __restrict__ nv,
                       f16* __restrict__ Opf, float* __restrict__ lp)
{
    __shared__ f16 sK[64 * 72];      // [j][d]
    __shared__ f16 sV[64 * 72];      // [d][j]

    const int tid  = threadIdx.x;
    const int wave = tid >> 6, lane = tid & 63;
    const int l15  = lane & 15, quad = lane >> 4;
    const int bh = blockIdx.x, b = bh >> 3, h = bh & 7;
    const int q0 = blockIdx.y * 128 + wave * 32;
    const int jh = blockIdx.z;

    f16x8 qf[2][2];
    const f16* qbase = qws + ((size_t)bh * NN + q0) * DH;
#pragma unroll
    for (int rt = 0; rt < 2; rt++)
#pragma unroll
        for (int ks = 0; ks < 2; ks++)
            qf[rt][ks] = *(const f16x8*)(qbase + (rt * 16 + l15) * DH + ks * 32 + quad * 8);

    int rowOk[2];
#pragma unroll
    for (int rt = 0; rt < 2; rt++)
        rowOk[rt] = mask[(size_t)b * NN + q0 + rt * 16 + l15];

    float pnull[2] = {0.0f, 0.0f};
    if (jh == 0) {
        float pn[2] = {0.f, 0.f};
#pragma unroll
        for (int ks = 0; ks < 2; ks++)
#pragma unroll
            for (int t = 0; t < 8; t++) {
                const float nkt = tanhf(nk[ks * 32 + quad * 8 + t]);
                pn[0] += (float)qf[0][ks][t] * nkt;
                pn[1] += (float)qf[1][ks][t] * nkt;
            }
#pragma unroll
        for (int rt = 0; rt < 2; rt++) {
            pn[rt] += __shfl_xor(pn[rt], 16);
            pn[rt] += __shfl_xor(pn[rt], 32);
            pnull[rt] = rowOk[rt] ? EXP2(pn[rt]) : 1.0f;
        }
    }
    float negsel[2];
#pragma unroll
    for (int rt = 0; rt < 2; rt++) {
        negsel[rt] = rowOk[rt] ? -1.0e30f : 0.0f;
        if (!rowOk[rt]) {
            const f16x8 zz = {(f16)0, (f16)0, (f16)0, (f16)0, (f16)0, (f16)0, (f16)0, (f16)0};
            qf[rt][0] = zz; qf[rt][1] = zz;
        }
    }

    f32x4 acc[2][4];
    f32x4 accl[2];
#pragma unroll
    for (int rt = 0; rt < 2; rt++)
#pragma unroll
        for (int reg = 0; reg < 4; reg++) {
            const float pr = __shfl(pnull[rt], quad * 4 + reg, 16);
            accl[rt][reg] = pr;
#pragma unroll
            for (int ds = 0; ds < 4; ds++)
                acc[rt][ds][reg] = pr * nv[ds * 16 + l15];
        }

    const f16* kg0 = kws + (size_t)bh * MM * DH;
    const f16* vg0 = vtws + (size_t)bh * DH * MM;
    const int sr = tid >> 2;
    const int sc = (tid & 3) * 16;
    const f16x4 vone = {(f16)1, (f16)1, (f16)1, (f16)1};
    const int jbeg = jh << 9, jend = jbeg + 512;

    for (int jc = jbeg; jc < jend; jc += 64) {
        uint4 kr0 = *(const uint4*)(kg0 + (size_t)(jc + sr) * DH + sc);
        uint4 kr1 = *(const uint4*)(kg0 + (size_t)(jc + sr) * DH + sc + 8);
        uint4 vr0 = *(const uint4*)(vg0 + (size_t)sr * MM + jc + sc);
        uint4 vr1 = *(const uint4*)(vg0 + (size_t)sr * MM + jc + sc + 8);
        int4 cmv[4];
#pragma unroll
        for (int jj = 0; jj < 4; jj++)
            cmv[jj] = *(const int4*)(cmask + (size_t)b * MM + jc + jj * 16 + quad * 4);

        __syncthreads();
        *(uint4*)(sK + sr * 72 + sc)     = kr0;
        *(uint4*)(sK + sr * 72 + sc + 8) = kr1;
        *(uint4*)(sV + sr * 72 + sc)     = vr0;
        *(uint4*)(sV + sr * 72 + sc + 8) = vr1;
        __syncthreads();

        f32x4 st[2][4];
#pragma unroll
        for (int rt = 0; rt < 2; rt++)
#pragma unroll
            for (int jj = 0; jj < 4; jj++) {
                st[rt][jj][0] = cmv[jj].x ? 0.0f : negsel[rt];
                st[rt][jj][1] = cmv[jj].y ? 0.0f : negsel[rt];
                st[rt][jj][2] = cmv[jj].z ? 0.0f : negsel[rt];
                st[rt][jj][3] = cmv[jj].w ? 0.0f : negsel[rt];
            }

#pragma unroll
        for (int ks = 0; ks < 2; ks++) {
            f16x8 kb[4];
#pragma unroll
            for (int jj = 0; jj < 4; jj++)
                kb[jj] = *(const f16x8*)(sK + (jj * 16 + l15) * 72 + ks * 32 + quad * 8);
#pragma unroll
            for (int rt = 0; rt < 2; rt++)
#pragma unroll
                for (int jj = 0; jj < 4; jj++)
                    st[rt][jj] = __builtin_amdgcn_mfma_f32_16x16x32_f16(
                        kb[jj], qf[rt][ks], st[rt][jj], 0, 0, 0);
        }

        f16x4 pa[2][4];
#pragma unroll
        for (int rt = 0; rt < 2; rt++)
#pragma unroll
            for (int jj = 0; jj < 4; jj++)
                pa[rt][jj] = pk4(EXP2(st[rt][jj][0]), EXP2(st[rt][jj][1]),
                                 EXP2(st[rt][jj][2]), EXP2(st[rt][jj][3]));

#pragma unroll
        for (int jj = 0; jj < 4; jj++) {
            f16x4 vb[4];
#pragma unroll
            for (int ds = 0; ds < 4; ds++)
                vb[ds] = *(const f16x4*)(sV + (ds * 16 + l15) * 72 + jj * 16 + quad * 4);
#pragma unroll
            for (int rt = 0; rt < 2; rt++) {
#pragma unroll
                for (int ds = 0; ds < 4; ds++)
                    acc[rt][ds] = __builtin_amdgcn_mfma_f32_16x16x16f16(
                        pa[rt][jj], vb[ds], acc[rt][ds], 0, 0, 0);
                accl[rt] = __builtin_amdgcn_mfma_f32_16x16x16f16(
                    pa[rt][jj], vone, accl[rt], 0, 0, 0);
            }
        }
    }

    // epilogue: normalized f16 partials + l
#pragma unroll
    for (int rt = 0; rt < 2; rt++) {
        float inv[4];
#pragma unroll
        for (int reg = 0; reg < 4; reg++)
            inv[reg] = 1.0f / fmaxf(accl[rt][reg], 1e-35f);
#pragma unroll
        for (int ds = 0; ds < 4; ds++)
#pragma unroll
            for (int reg = 0; reg < 4; reg++) {
                const int r = q0 + rt * 16 + quad * 4 + reg;
                Opf[((size_t)jh * 8192 + b * 2048 + r) * 512 + h * 64 + ds * 16 + l15] =
                    (f16)(acc[rt][ds][reg] * inv[reg]);
            }
    }
    if (l15 == 0) {
#pragma unroll
        for (int rt = 0; rt < 2; rt++)
#pragma unroll
            for (int reg = 0; reg < 4; reg++)
                lp[((size_t)jh * 32 + bh) * 2048 + q0 + rt * 16 + quad * 4 + reg] =
                    accl[rt][reg];
    }
}

// ---------------------------------------------------------------------------
// Merge 4 j-partials: O = sum(Ohat_p * l_p) / sum(l_p) -> f16 of16.
// ---------------------------------------------------------------------------
__global__ void merge_k(const f16* __restrict__ Opf, const float* __restrict__ lp,
                        f16* __restrict__ of16)
{
    const int i = blockIdx.x * 256 + threadIdx.x;   // 1,048,576 threads
    const int row = i >> 7;                          // 0..8191
    const int c4  = i & 127;
    const int b = row >> 11, n = row & 2047, h = c4 >> 4;
    float w[4], den = 0.f;
#pragma unroll
    for (int jh = 0; jh < 4; jh++) {
        w[jh] = lp[((size_t)jh * 32 + b * 8 + h) * 2048 + n];
        den += w[jh];
    }
    const float inv = 1.0f / den;
    float v0 = 0, v1 = 0, v2 = 0, v3 = 0;
#pragma unroll
    for (int jh = 0; jh < 4; jh++) {
        f16x4 o = *(const f16x4*)(Opf + ((size_t)jh * 8192 + row) * 512 + c4 * 4);
        v0 += (float)o[0] * w[jh];
        v1 += (float)o[1] * w[jh];
        v2 += (float)o[2] * w[jh];
        v3 += (float)o[3] * w[jh];
    }
    f16x4 r = pk4(v0 * inv, v1 * inv, v2 * inv, v3 * inv);
    *(f16x4*)(of16 + (size_t)row * 512 + c4 * 4) = r;
}

// ---------------------------------------------------------------------------
// Final GEMM: out = O(f16) @ Wo(f16 hi/lo) + bias.  2 MFMAs per sub-tile.
// ---------------------------------------------------------------------------
__launch_bounds__(256)
__global__ void mgemm2(const f16* __restrict__ A, const f16* __restrict__ Bh,
                       const f16* __restrict__ Bl,
                       float* __restrict__ o32, const float* __restrict__ bias,
                       int K)
{
    __shared__ f16 sA[128 * 36];
    __shared__ f16 sBh[64 * 36], sBl[64 * 36];

    const int tid  = threadIdx.x;
    const int wave = tid >> 6, lane = tid & 63;
    const int l15  = lane & 15, quad = lane >> 4;
    const size_t r0 = (size_t)blockIdx.x * 128;
    const int c0 = blockIdx.y * 64;

    const int sr = tid >> 2;
    const int sc = (tid & 3) * 8;

    f32x4 acc[2][4] = {};

    for (int k0 = 0; k0 < K; k0 += 32) {
        uint4 a0 = *(const uint4*)(A + (r0 + sr) * K + k0 + sc);
        uint4 a1 = *(const uint4*)(A + (r0 + 64 + sr) * K + k0 + sc);
        uint4 bh = *(const uint4*)(Bh + (size_t)(c0 + sr) * K + k0 + sc);
        uint4 bl = *(const uint4*)(Bl + (size_t)(c0 + sr) * K + k0 + sc);
        __syncthreads();
        *(uint4*)(sA + sr * 36 + sc)        = a0;
        *(uint4*)(sA + (64 + sr) * 36 + sc) = a1;
        *(uint4*)(sBh + sr * 36 + sc)       = bh;
        *(uint4*)(sBl + sr * 36 + sc)       = bl;
        __syncthreads();

        f16x8 a[2], b_h[4], b_l[4];
#pragma unroll
        for (int rt = 0; rt < 2; rt++)
            a[rt] = *(const f16x8*)(sA + (wave * 32 + rt * 16 + l15) * 36 + quad * 8);
#pragma unroll
        for (int ct = 0; ct < 4; ct++) {
            b_h[ct] = *(const f16x8*)(sBh + (ct * 16 + l15) * 36 + quad * 8);
            b_l[ct] = *(const f16x8*)(sBl + (ct * 16 + l15) * 36 + quad * 8);
        }
#pragma unroll
        for (int rt = 0; rt < 2; rt++)
#pragma unroll
            for (int ct = 0; ct < 4; ct++) {
                acc[rt][ct] = __builtin_amdgcn_mfma_f32_16x16x32_f16(a[rt], b_h[ct], acc[rt][ct], 0, 0, 0);
                acc[rt][ct] = __builtin_amdgcn_mfma_f32_16x16x32_f16(a[rt], b_l[ct], acc[rt][ct], 0, 0, 0);
            }
    }

#pragma unroll
    for (int rt = 0; rt < 2; rt++)
#pragma unroll
        for (int ct = 0; ct < 4; ct++) {
            const int col = c0 + ct * 16 + l15;
            const float bv = bias[col];
#pragma unroll
            for (int reg = 0; reg < 4; reg++) {
                const size_t row = r0 + wave * 32 + rt * 16 + quad * 4 + reg;
                o32[row * 512 + col] = acc[rt][ct][reg] + bv;
            }
        }
}

extern "C" void kernel_launch(void* const* d_in, const int* in_sizes, int n_in,
                              void* d_out, int out_size, void* d_ws, size_t ws_size,
                              hipStream_t stream)
{
    const float* x    = (const float*)d_in[0];
    const float* ctx  = (const float*)d_in[1];
    const int*   mask = (const int*)d_in[2];
    const int*   cmsk = (const int*)d_in[3];
    const float* Wq   = (const float*)d_in[4];
    const float* Wkv  = (const float*)d_in[5];
    const float* Wo   = (const float*)d_in[6];
    const float* bo   = (const float*)d_in[7];
    const float* nk   = (const float*)d_in[8];
    const float* nv   = (const float*)d_in[9];
    float* out = (float*)d_out;

    const size_t S = (size_t)BB * HEADS * NN * DH;  // 4,194,304 elems

    f16* qws = (f16*)d_ws;                  // 8 MB
    f16* kws = qws + S;                     // 8 MB
    f16* vt  = kws + S;                     // 8 MB
    f16* wq16  = vt + S;                    // 0.5 MB
    f16* wkv16 = wq16 + 512 * 512;          // 1 MB
    f16* woh = wkv16 + 512 * 1024;          // 0.5 MB
    f16* wol = woh + 512 * 512;             // 0.5 MB
    float* lp = (float*)(wol + 512 * 512);  // 1 MB
    f16* Opf = (f16*)(lp + 4 * 32 * 2048);  // 32 MB
    f16* of16 = qws;                        // alias (qws dead after attn_k)

    wprep_k<<<512, 256, 0, stream>>>(Wq, Wkv, Wo, wq16, wkv16, woh, wol);
    proj_k<<<dim3(64, 12), 256, 0, stream>>>(x, ctx, wq16, wkv16, qws, kws, vt);
    attn_k<<<dim3(32, 16, 4), 256, 0, stream>>>(qws, kws, vt, mask, cmsk, nk, nv, Opf, lp);
    merge_k<<<4096, 256, 0, stream>>>(Opf, lp, of16);
    mgemm2<<<dim3(64, 8), 256, 0, stream>>>(of16, woh, wol, out, bo, 512);
}